// Round 8
// baseline (237.802 us; speedup 1.0000x reference)
//
#include <hip/hip_runtime.h>

typedef __bf16 bf16x8 __attribute__((ext_vector_type(8)));
typedef unsigned short us8 __attribute__((ext_vector_type(8)));
typedef unsigned short us2 __attribute__((ext_vector_type(2)));
typedef float f32x16 __attribute__((ext_vector_type(16)));

#define N_IMG 32
#define CI 16
#define HH 256
#define WW 256
#define CO 64
#define OHH 254
#define OWW 254

#define XS_W 258              // 256 + 2 zero-pad columns
#define SC 24                 // shorts per (row,w) cell: 48B stride, bank-balanced
#define NSTRIP 24             // 32*24 = 768 blocks = exactly 3 resident/CU
#define WP_SHORTS (CO * 160)
// ws layout: wp at 0 (20 KB), xt (NHWC bf16, 64 MB) at 64 KB
#define XT_OFF_SHORTS 32768
#define XT_SHORTS ((size_t)N_IMG * HH * WW * CI)
#define WS_NEEDED (((size_t)XT_OFF_SHORTS + XT_SHORTS) * 2)

__device__ __forceinline__ unsigned short f2bf(float f) {
  union { float f; unsigned u; } v; v.f = f;
  return (unsigned short)((v.u + 0x7FFFu + ((v.u >> 16) & 1u)) >> 16);  // RNE
}

#if defined(__has_builtin)
#if __has_builtin(__builtin_amdgcn_cvt_pk_bf16_f32)
#define HAVE_CVT_PK 1
#endif
#endif

__device__ __forceinline__ us2 cvt2(float a, float b) {
#ifdef HAVE_CVT_PK
  typedef __bf16 bf16x2 __attribute__((ext_vector_type(2)));
  bf16x2 r = __builtin_amdgcn_cvt_pk_bf16_f32(a, b);  // lo=a, hi=b, RNE
  return __builtin_bit_cast(us2, r);
#else
  us2 r; r[0] = f2bf(a); r[1] = f2bf(b); return r;
#endif
}

__device__ __forceinline__ float fast_tanh(float x) {
  float cx = fminf(fmaxf(x, -15.f), 15.f);
  float e = __expf(2.f * cx);
  return (e - 1.f) / (e + 1.f);
}

// ---- prep: weights+bias -> bf16 A-side layout wp[oc][tap*16+ci] (20 KB) ----
__global__ void prep_w(const float* __restrict__ wg, const float* __restrict__ bg,
                       unsigned short* __restrict__ wp) {
  int idx = blockIdx.x * 256 + threadIdx.x;
  if (idx >= WP_SHORTS) return;
  int oc = idx / 160;
  int k = idx - oc * 160;
  int tap = k >> 4, ci = k & 15;
  float v;
  if (tap < 9)      v = wg[oc * 144 + ci * 9 + tap];
  else if (ci == 0) v = bg[oc];
  else              v = 0.f;
  wp[idx] = f2bf(v);
}

// ---- NCHW f32 -> NHWC bf16 streaming transform (the 16-way plane gather,
// hoisted OUT of the barriered conv loop into a pure streaming kernel where
// 8192 independent blocks hide the gather latency entirely). One block =
// one (n,h) input row; thread t = column w. Same RNE cvt as before -> the
// conv consumes bit-identical bf16 values.
__global__ __launch_bounds__(256)
void nhwc_cvt(const float* __restrict__ xg, unsigned short* __restrict__ xt) {
  const int b = blockIdx.x;            // n*256 + h
  const int t = threadIdx.x;           // w
  const float* src = xg + (size_t)(b >> 8) * (CI * HH * WW) + (size_t)(b & 255) * WW + t;
  float v[16];
#pragma unroll
  for (int j = 0; j < 16; ++j) v[j] = src[(size_t)j * (HH * WW)];
  union { us8 v8[2]; us2 v2[8]; } pk;
#pragma unroll
  for (int j = 0; j < 8; ++j) pk.v2[j] = cvt2(v[2 * j], v[2 * j + 1]);
  unsigned short* dst = xt + ((size_t)b * WW + t) * 16;
  *(us8*)dst = pk.v8[0];        // global_store_dwordx4
  *(us8*)(dst + 8) = pk.v8[1];  // global_store_dwordx4
}

// ---- fused conv+min+tanh: rolling-window strip kernel over NHWC bf16 ----
// R7 structure with the staging gather replaced by 2 contiguous dwordx4
// loads per thread per row (32 B of [w][ci] cell, already bf16 -- no cvt in
// the loop, v is 4 VGPRs instead of 16). Diagnosis: conv was ~73us (3x its
// HBM floor) with all pipes <25% across R0-R7; barriers/prefetch-distance/
// LDS-layout all proven non-levers; the per-row 16-plane scattered dword
// chain was the remaining intrinsic serializer. Ring/barrier logic and the
// MFMA/fmin/tanh core are unchanged from R7 (bit-identical output).
__global__ __launch_bounds__(256, 3)
void conv_fused(const unsigned short* __restrict__ xt,
                const unsigned short* __restrict__ wp, float* __restrict__ out) {
  __shared__ __align__(16) unsigned short xs[4 * XS_W * SC];  // 48.4 KB -> 3/CU
  const int t = threadIdx.x;
  const int n = blockIdx.x / NSTRIP;
  const int s = blockIdx.x - n * NSTRIP;
  // 254 rows over 24 strips: 14 strips of 11 rows, 10 strips of 10 rows
  const int oh0 = s * 10 + (s < 14 ? s : 14);
  const int nrows = (s < 14) ? 11 : 10;
  const int oh1 = oh0 + nrows;

  // this thread's cell column in xt: row r -> base + r*4096 shorts
  const unsigned short* srcC = xt + ((size_t)n * HH * WW + t) * 16;

  // ---- prologue: stage input rows oh0..oh0+2 into their ring slots ----
  {
#pragma unroll
    for (int r = 0; r < 3; ++r) {
      const unsigned short* p = srcC + (size_t)(oh0 + r) * (WW * 16);
      us8 a = *(const us8*)p;
      us8 b = *(const us8*)(p + 8);
      const int slot = (oh0 + r) & 3;
      *(us8*)(xs + (slot * XS_W + t) * SC) = a;      // ds_write_b128
      *(us8*)(xs + (slot * XS_W + t) * SC + 8) = b;  // ds_write_b128
    }
  }
  if (t < 128) {  // zero pad columns w=256,257 for all 4 ring slots (persist)
    const int slot = t >> 5, rem = t & 31;
    xs[(slot * XS_W + 256 + (rem >> 4)) * SC + (rem & 15)] = 0;
  }

  const int lane = t & 63, wave = t >> 6;
  const int lr = lane & 31, qh = lane >> 5;

  // preload A-frags ONCE into registers (2 mt x 10 taps x 4 VGPR = 80 VGPRs)
  const unsigned short* wpl = wp + lr * 160 + qh * 8;
  bf16x8 afrag[2][10];
#pragma unroll
  for (int mt = 0; mt < 2; ++mt)
#pragma unroll
    for (int tap = 0; tap < 10; ++tap)
      afrag[mt][tap] =
          __builtin_bit_cast(bf16x8, *(const us8*)(wpl + mt * 32 * 160 + tap * 16));

  us8 onev = {};
  if (qh == 0) onev[0] = 0x3F80;
  const bf16x8 xone = __builtin_bit_cast(bf16x8, onev);

  const int pb = wave * 64;  // this wave's 64-pixel strip

  // prime the prefetch: v <- row oh0+3 (consumed by iter oh0's stage phase)
  us8 va, vb;
  {
    const unsigned short* p = srcC + (size_t)(oh0 + 3) * (WW * 16);
    va = *(const us8*)p;
    vb = *(const us8*)(p + 8);
  }

  __syncthreads();

  for (int oh = oh0; oh < oh1; ++oh) {
    // ---- phase 1: MFMA row oh from ring slots oh..oh+2 (LDS only) ----
    float vmin[2];
#pragma unroll
    for (int nt = 0; nt < 2; ++nt) {  // sequential nt: acc = 32 VGPR not 64
      f32x16 acc0, acc1;
#pragma unroll
      for (int e = 0; e < 16; ++e) { acc0[e] = 0.f; acc1[e] = 0.f; }
#pragma unroll
      for (int tap = 0; tap < 9; ++tap) {
        const int kh = tap / 3, kw = tap - kh * 3;
        const int slot = (oh + kh) & 3;
        bf16x8 xf = __builtin_bit_cast(
            bf16x8,
            *(const us8*)(xs + (slot * XS_W + pb + nt * 32 + lr + kw) * SC + qh * 8));
        acc0 = __builtin_amdgcn_mfma_f32_32x32x16_bf16(afrag[0][tap], xf, acc0, 0, 0, 0);
        acc1 = __builtin_amdgcn_mfma_f32_32x32x16_bf16(afrag[1][tap], xf, acc1, 0, 0, 0);
      }
      // bias tap: B = e_{k=144}
      acc0 = __builtin_amdgcn_mfma_f32_32x32x16_bf16(afrag[0][9], xone, acc0, 0, 0, 0);
      acc1 = __builtin_amdgcn_mfma_f32_32x32x16_bf16(afrag[1][9], xone, acc1, 0, 0, 0);

      // tree min: depth 5 instead of a 31-deep serial chain (bit-exact)
      f32x16 m;
#pragma unroll
      for (int e = 0; e < 16; ++e) m[e] = fminf(acc0[e], acc1[e]);
#pragma unroll
      for (int e = 0; e < 8; ++e) m[e] = fminf(m[e], m[e + 8]);
#pragma unroll
      for (int e = 0; e < 4; ++e) m[e] = fminf(m[e], m[e + 4]);
      float mv = fminf(fminf(m[0], m[1]), fminf(m[2], m[3]));
      mv = fminf(mv, __shfl_xor(mv, 32, 64));
      vmin[nt] = fast_tanh(fast_tanh(mv));
    }

    // pin phase order: stage/loads must not be hoisted above the MFMA phase
    __builtin_amdgcn_sched_barrier(0);

    // ---- phase 2: write v (row oh+3, loaded LAST iteration) to its slot ----
    if (oh + 1 < oh1) {
      const int slot = (oh + 3) & 3;
      *(us8*)(xs + (slot * XS_W + t) * SC) = va;
      *(us8*)(xs + (slot * XS_W + t) * SC + 8) = vb;
    }

    // ---- phase 3: issue loads for row oh+4 (consumed NEXT iteration) ----
    if (oh + 2 < oh1) {
      const unsigned short* p = srcC + (size_t)(oh + 4) * (WW * 16);
      va = *(const us8*)p;
      vb = *(const us8*)(p + 8);
    }

    // ---- phase 4: store output row oh ----
    const float res = (lane < 32) ? vmin[0] : vmin[1];
    const int ow = pb + lane;
    if (ow < OWW) out[((size_t)n * OHH + oh) * OWW + ow] = res;

    __syncthreads();
  }
}

// ================= fallback (round-1 kernel) if ws too small ================
#define XS_C 24
#define WS_K 168
__global__ __launch_bounds__(256, 2)
void conv_min_tanh(const float* __restrict__ xg, const float* __restrict__ wg,
                   const float* __restrict__ bg, float* __restrict__ out) {
  __shared__ __align__(16) unsigned short xs[3 * XS_W * XS_C];
  __shared__ __align__(16) unsigned short ws[CO * WS_K];
  const int t = threadIdx.x;
  const int n = blockIdx.x / OHH;
  const int oh = blockIdx.x % OHH;
#pragma unroll
  for (int i = 0; i < 36; ++i) {
    int f = i * 256 + t;
    int oc = f / 144;
    int r = f - oc * 144;
    int ci = r / 9;
    int tap = r - ci * 9;
    ws[oc * WS_K + tap * 16 + ci] = f2bf(wg[f]);
  }
  if (t < CO) ws[t * WS_K + 144] = f2bf(bg[t]);
  for (int i = t; i < CO * 15; i += 256) {
    int oc = i / 15;
    ws[oc * WS_K + 145 + (i - oc * 15)] = 0;
  }
  {
    const size_t base_n = (size_t)n * CI * HH * WW;
#pragma unroll
    for (int kh = 0; kh < 3; ++kh) {
#pragma unroll
      for (int half = 0; half < 2; ++half) {
        float v[8];
#pragma unroll
        for (int j = 0; j < 8; ++j) {
          int ci = half * 8 + j;
          v[j] = xg[base_n + ((size_t)ci * HH + (oh + kh)) * WW + t];
        }
        us8 pk;
#pragma unroll
        for (int j = 0; j < 8; ++j) pk[j] = f2bf(v[j]);
        *(us8*)(xs + (kh * XS_W + t) * XS_C + half * 8) = pk;
      }
    }
  }
  if (t < 96) {
    int kh = t >> 5;
    int rem = t & 31;
    int w = 256 + (rem >> 4);
    int ci = rem & 15;
    xs[(kh * XS_W + w) * XS_C + ci] = 0;
  }
  __syncthreads();
  const int lane = t & 63, wave = t >> 6;
  const int lr = lane & 31, qh = lane >> 5;
  bf16x8 afrag[2][10];
#pragma unroll
  for (int mt = 0; mt < 2; ++mt) {
    const unsigned short* wq = ws + (mt * 32 + lr) * WS_K + qh * 8;
#pragma unroll
    for (int tap = 0; tap < 10; ++tap)
      afrag[mt][tap] = __builtin_bit_cast(bf16x8, *(const us8*)(wq + tap * 16));
  }
  f32x16 acc[2][2];
#pragma unroll
  for (int a = 0; a < 2; ++a)
#pragma unroll
    for (int b = 0; b < 2; ++b)
#pragma unroll
      for (int e = 0; e < 16; ++e) acc[a][b][e] = 0.f;
  const unsigned short* xq = xs + (wave * 64 + lr) * XS_C + qh * 8;
#pragma unroll
  for (int tap = 0; tap < 9; ++tap) {
    const int kh = tap / 3, kw = tap - kh * 3;
#pragma unroll
    for (int nt = 0; nt < 2; ++nt) {
      bf16x8 xf = __builtin_bit_cast(
          bf16x8, *(const us8*)(xq + (kh * XS_W + nt * 32 + kw) * XS_C));
      acc[0][nt] = __builtin_amdgcn_mfma_f32_32x32x16_bf16(afrag[0][tap], xf,
                                                           acc[0][nt], 0, 0, 0);
      acc[1][nt] = __builtin_amdgcn_mfma_f32_32x32x16_bf16(afrag[1][tap], xf,
                                                           acc[1][nt], 0, 0, 0);
    }
  }
  {
    us8 one = {};
    if (qh == 0) one[0] = 0x3F80;
    bf16x8 xone = __builtin_bit_cast(bf16x8, one);
#pragma unroll
    for (int nt = 0; nt < 2; ++nt) {
      acc[0][nt] = __builtin_amdgcn_mfma_f32_32x32x16_bf16(afrag[0][9], xone,
                                                           acc[0][nt], 0, 0, 0);
      acc[1][nt] = __builtin_amdgcn_mfma_f32_32x32x16_bf16(afrag[1][9], xone,
                                                           acc[1][nt], 0, 0, 0);
    }
  }
  float vmin[2];
#pragma unroll
  for (int nt = 0; nt < 2; ++nt) {
    float v = acc[0][nt][0];
#pragma unroll
    for (int e = 1; e < 16; ++e) v = fminf(v, acc[0][nt][e]);
#pragma unroll
    for (int e = 0; e < 16; ++e) v = fminf(v, acc[1][nt][e]);
    v = fminf(v, __shfl_xor(v, 32, 64));
    vmin[nt] = fast_tanh(fast_tanh(v));
  }
  float res = (lane < 32) ? vmin[0] : vmin[1];
  int ow = wave * 64 + lane;
  if (ow < OWW) out[((size_t)n * OHH + oh) * OWW + ow] = res;
}

extern "C" void kernel_launch(void* const* d_in, const int* in_sizes, int n_in,
                              void* d_out, int out_size, void* d_ws, size_t ws_size,
                              hipStream_t stream) {
  const float* x = (const float*)d_in[0];
  const float* w = (const float*)d_in[1];
  const float* b = (const float*)d_in[2];
  float* out = (float*)d_out;
  if (ws_size >= WS_NEEDED) {
    unsigned short* wp = (unsigned short*)d_ws;
    unsigned short* xt = (unsigned short*)d_ws + XT_OFF_SHORTS;
    prep_w<<<dim3((WP_SHORTS + 255) / 256), dim3(256), 0, stream>>>(w, b, wp);
    nhwc_cvt<<<dim3(N_IMG * HH), dim3(256), 0, stream>>>(x, xt);
    conv_fused<<<dim3(N_IMG * NSTRIP), dim3(256), 0, stream>>>(xt, wp, out);
  } else {
    conv_min_tanh<<<dim3(N_IMG * OHH), dim3(256), 0, stream>>>(x, w, b, out);
  }
}

// Round 9
// 209.734 us; speedup vs baseline: 1.1338x; 1.1338x over previous
//
#include <hip/hip_runtime.h>

typedef __bf16 bf16x8 __attribute__((ext_vector_type(8)));
typedef unsigned short us8 __attribute__((ext_vector_type(8)));
typedef unsigned short us2 __attribute__((ext_vector_type(2)));
typedef float f32x16 __attribute__((ext_vector_type(16)));

#define N_IMG 32
#define CI 16
#define HH 256
#define WW 256
#define CO 64
#define OHH 254
#define OWW 254

#define XS_W 258   // 256 + 2 zero-pad columns
#define SC 24      // shorts per (row,w) cell: 48B stride, bank-balanced b128
#define NSTRIP 16  // 32*16 = 512 blocks of 512 thr = exactly 2 resident/CU
#define WP_SHORTS (CO * 160)
#define WS_NEEDED ((size_t)WP_SHORTS * 2)

__device__ __forceinline__ unsigned short f2bf(float f) {
  union { float f; unsigned u; } v; v.f = f;
  return (unsigned short)((v.u + 0x7FFFu + ((v.u >> 16) & 1u)) >> 16);  // RNE
}

#if defined(__has_builtin)
#if __has_builtin(__builtin_amdgcn_cvt_pk_bf16_f32)
#define HAVE_CVT_PK 1
#endif
#endif

__device__ __forceinline__ us2 cvt2(float a, float b) {
#ifdef HAVE_CVT_PK
  typedef __bf16 bf16x2 __attribute__((ext_vector_type(2)));
  bf16x2 r = __builtin_amdgcn_cvt_pk_bf16_f32(a, b);  // lo=a, hi=b, RNE
  return __builtin_bit_cast(us2, r);
#else
  us2 r; r[0] = f2bf(a); r[1] = f2bf(b); return r;
#endif
}

__device__ __forceinline__ float fast_tanh(float x) {
  float cx = fminf(fmaxf(x, -15.f), 15.f);
  float e = __expf(2.f * cx);
  return (e - 1.f) / (e + 1.f);
}

// ---- prep: weights+bias -> bf16 A-side layout wp[oc][tap*16+ci] (20 KB) ----
__global__ void prep_w(const float* __restrict__ wg, const float* __restrict__ bg,
                       unsigned short* __restrict__ wp) {
  int idx = blockIdx.x * 256 + threadIdx.x;
  if (idx >= WP_SHORTS) return;
  int oc = idx / 160;
  int k = idx - oc * 160;
  int tap = k >> 4, ci = k & 15;
  float v;
  if (tap < 9)      v = wg[oc * 144 + ci * 9 + tap];
  else if (ci == 0) v = bg[oc];
  else              v = 0.f;
  wp[idx] = f2bf(v);
}

// ---- fused conv+min+tanh: OC-SPLIT rolling-window kernel ----
// DIAGNOSIS (R0-R8): conv pinned at ~70us with ALL pipes <25% across every
// loop-structure/LDS/traffic/barrier variant. The untouched invariant:
// afrag = 80 VGPR of weights per wave -> ~150-200 total -> 8-9 waves/CU
// (Occupancy 28-32%), i.e. 2.25 waves/SIMD -- too few to overlap each
// wave's serial row path. Per m69 waves/CU halves at VGPR>128.
// FIX: 512-thread blocks, 8 waves = (oc-half mt) x (4 pixel strips).
// afrag halves to 40 VGPR (one 32-oc half), acc 16 (sequential nt),
// ~100 total -> 16 waves/CU (2 blocks), per-wave path halves (20 MFMA/row).
// New cost: per-row cross-wave min exchange via parity-double-buffered
// pmin LDS (4KB); both mt waves write 32-oc partial mins before the
// existing per-row barrier; mt=0 waves combine+tanh+store after it.
// fmin assoc/comm over identical value set -> bit-identical output.
// Ring (4 slots, slot=row&3) and barrier-per-row proof unchanged from R3/R7.
// pmin race-freedom: epilogue(oh) reads pmin[oh&1] between barrier(oh) and
// barrier(oh+1); next write of pmin[oh&1] is iter oh+2 phase1, after
// barrier(oh+1). Staging: NCHW gather split across 512 thr (thread =
// (w, ci-half), 8 dword loads/row), loaded one iter ahead (R7 pattern).
__global__ __launch_bounds__(512, 4)
void conv_fused(const float* __restrict__ xg, const unsigned short* __restrict__ wp,
                float* __restrict__ out) {
  __shared__ __align__(16) unsigned short xs[4 * XS_W * SC];  // 48.4 KB
  __shared__ float pmin[2][2][256];                           // 4 KB, [par][mt][pix]
  const int t = threadIdx.x;
  const int n = blockIdx.x / NSTRIP;
  const int s = blockIdx.x - n * NSTRIP;
  // 254 rows over 16 strips: 14 strips of 16 rows, 2 strips of 15
  const int oh0 = (s < 14) ? 16 * s : 224 + 15 * (s - 14);
  const int nrows = (s < 14) ? 16 : 15;
  const int oh1 = oh0 + nrows;

  // staging identity: thread t covers column w = t&255, ci-half = t>>8
  const int w = t & 255, half = t >> 8;
  const float* srcT =
      xg + (size_t)n * (CI * HH * WW) + (size_t)(half * 8) * (HH * WW) + w;

  // ---- prologue: stage input rows oh0..oh0+2 into ring slots (8 ld/row) ----
#pragma unroll
  for (int r = 0; r < 3; ++r) {
    float v[8];
#pragma unroll
    for (int j = 0; j < 8; ++j) v[j] = srcT[((size_t)j * HH + (oh0 + r)) * WW];
    union { us8 v8; us2 v2[4]; } pk;
#pragma unroll
    for (int j = 0; j < 4; ++j) pk.v2[j] = cvt2(v[2 * j], v[2 * j + 1]);
    const int slot = (oh0 + r) & 3;
    *(us8*)(xs + (slot * XS_W + w) * SC + half * 8) = pk.v8;  // ds_write_b128
  }
  if (t < 128) {  // zero pad columns w=256,257 for all 4 ring slots (persist)
    const int slot = t >> 5, rem = t & 31;
    xs[(slot * XS_W + 256 + (rem >> 4)) * SC + (rem & 15)] = 0;
  }

  const int lane = t & 63, wave = t >> 6;
  const int lr = lane & 31, qh = lane >> 5;
  const int mt = wave >> 2;        // this wave's 32-oc half
  const int pb = (wave & 3) * 64;  // this wave's 64-pixel strip

  // preload A-frags ONCE: 10 taps x 4 VGPR = 40 VGPRs (one oc-half)
  const unsigned short* wpl = wp + (mt * 32 + lr) * 160 + qh * 8;
  bf16x8 afrag[10];
#pragma unroll
  for (int tap = 0; tap < 10; ++tap)
    afrag[tap] = __builtin_bit_cast(bf16x8, *(const us8*)(wpl + tap * 16));

  us8 onev = {};
  if (qh == 0) onev[0] = 0x3F80;
  const bf16x8 xone = __builtin_bit_cast(bf16x8, onev);

  // prime the prefetch: v <- row oh0+3 (consumed by iter oh0's stage phase)
  float v[8];
#pragma unroll
  for (int j = 0; j < 8; ++j) v[j] = srcT[((size_t)j * HH + (oh0 + 3)) * WW];

  __syncthreads();

  for (int oh = oh0; oh < oh1; ++oh) {
    const int par = oh & 1;

    // ---- phase 1: MFMA row oh (20 MFMA/wave) + 32-oc partial min ----
#pragma unroll
    for (int nt = 0; nt < 2; ++nt) {
      f32x16 acc;
#pragma unroll
      for (int e = 0; e < 16; ++e) acc[e] = 0.f;
#pragma unroll
      for (int tap = 0; tap < 9; ++tap) {
        const int kh = tap / 3, kw = tap - kh * 3;
        const int slot = (oh + kh) & 3;
        bf16x8 xf = __builtin_bit_cast(
            bf16x8,
            *(const us8*)(xs + (slot * XS_W + pb + nt * 32 + lr + kw) * SC + qh * 8));
        acc = __builtin_amdgcn_mfma_f32_32x32x16_bf16(afrag[tap], xf, acc, 0, 0, 0);
      }
      // bias tap: B = e_{k=144}
      acc = __builtin_amdgcn_mfma_f32_32x32x16_bf16(afrag[9], xone, acc, 0, 0, 0);

      // tree min over this lane's 16 oc (bit-exact reassociation)
      f32x16 m = acc;
#pragma unroll
      for (int e = 0; e < 8; ++e) m[e] = fminf(m[e], m[e + 8]);
#pragma unroll
      for (int e = 0; e < 4; ++e) m[e] = fminf(m[e], m[e + 4]);
      float mv = fminf(fminf(m[0], m[1]), fminf(m[2], m[3]));
      mv = fminf(mv, __shfl_xor(mv, 32, 64));  // min over the 32-oc half
      if (lane < 32) pmin[par][mt][pb + nt * 32 + lane] = mv;
    }

    // ---- phase 2: write v (row oh+3, loaded LAST iter) into its slot ----
    if (oh + 1 < oh1) {
      union { us8 v8; us2 v2[4]; } pk;
#pragma unroll
      for (int j = 0; j < 4; ++j) pk.v2[j] = cvt2(v[2 * j], v[2 * j + 1]);
      const int slot = (oh + 3) & 3;
      *(us8*)(xs + (slot * XS_W + w) * SC + half * 8) = pk.v8;
    }

    // ---- phase 3: issue loads for row oh+4 (consumed NEXT iteration) ----
    if (oh + 2 < oh1) {
#pragma unroll
      for (int j = 0; j < 8; ++j) v[j] = srcT[((size_t)j * HH + (oh + 4)) * WW];
    }

    __syncthreads();  // publishes: staged row, pmin partials

    // ---- phase 4: epilogue (mt=0 waves): combine halves, tanh^2, store ----
    if (mt == 0) {
      const float a = pmin[par][0][pb + lane];
      const float b = pmin[par][1][pb + lane];
      const float r = fast_tanh(fast_tanh(fminf(a, b)));
      const int ow = pb + lane;
      if (ow < OWW) out[((size_t)n * OHH + oh) * OWW + ow] = r;
    }
  }
}

// ================= fallback (round-1 kernel) if ws too small ================
#define XS_C 24
#define WS_K 168
__global__ __launch_bounds__(256, 2)
void conv_min_tanh(const float* __restrict__ xg, const float* __restrict__ wg,
                   const float* __restrict__ bg, float* __restrict__ out) {
  __shared__ __align__(16) unsigned short xs[3 * XS_W * XS_C];
  __shared__ __align__(16) unsigned short ws[CO * WS_K];
  const int t = threadIdx.x;
  const int n = blockIdx.x / OHH;
  const int oh = blockIdx.x % OHH;
#pragma unroll
  for (int i = 0; i < 36; ++i) {
    int f = i * 256 + t;
    int oc = f / 144;
    int r = f - oc * 144;
    int ci = r / 9;
    int tap = r - ci * 9;
    ws[oc * WS_K + tap * 16 + ci] = f2bf(wg[f]);
  }
  if (t < CO) ws[t * WS_K + 144] = f2bf(bg[t]);
  for (int i = t; i < CO * 15; i += 256) {
    int oc = i / 15;
    ws[oc * WS_K + 145 + (i - oc * 15)] = 0;
  }
  {
    const size_t base_n = (size_t)n * CI * HH * WW;
#pragma unroll
    for (int kh = 0; kh < 3; ++kh) {
#pragma unroll
      for (int half = 0; half < 2; ++half) {
        float v[8];
#pragma unroll
        for (int j = 0; j < 8; ++j) {
          int ci = half * 8 + j;
          v[j] = xg[base_n + ((size_t)ci * HH + (oh + kh)) * WW + t];
        }
        us8 pk;
#pragma unroll
        for (int j = 0; j < 8; ++j) pk[j] = f2bf(v[j]);
        *(us8*)(xs + (kh * XS_W + t) * XS_C + half * 8) = pk;
      }
    }
  }
  if (t < 96) {
    int kh = t >> 5;
    int rem = t & 31;
    int w = 256 + (rem >> 4);
    int ci = rem & 15;
    xs[(kh * XS_W + w) * XS_C + ci] = 0;
  }
  __syncthreads();
  const int lane = t & 63, wave = t >> 6;
  const int lr = lane & 31, qh = lane >> 5;
  bf16x8 afrag[2][10];
#pragma unroll
  for (int mt = 0; mt < 2; ++mt) {
    const unsigned short* wq = ws + (mt * 32 + lr) * WS_K + qh * 8;
#pragma unroll
    for (int tap = 0; tap < 10; ++tap)
      afrag[mt][tap] = __builtin_bit_cast(bf16x8, *(const us8*)(wq + tap * 16));
  }
  f32x16 acc[2][2];
#pragma unroll
  for (int a = 0; a < 2; ++a)
#pragma unroll
    for (int b = 0; b < 2; ++b)
#pragma unroll
      for (int e = 0; e < 16; ++e) acc[a][b][e] = 0.f;
  const unsigned short* xq = xs + (wave * 64 + lr) * XS_C + qh * 8;
#pragma unroll
  for (int tap = 0; tap < 9; ++tap) {
    const int kh = tap / 3, kw = tap - kh * 3;
#pragma unroll
    for (int nt = 0; nt < 2; ++nt) {
      bf16x8 xf = __builtin_bit_cast(
          bf16x8, *(const us8*)(xq + (kh * XS_W + nt * 32 + kw) * XS_C));
      acc[0][nt] = __builtin_amdgcn_mfma_f32_32x32x16_bf16(afrag[0][tap], xf,
                                                           acc[0][nt], 0, 0, 0);
      acc[1][nt] = __builtin_amdgcn_mfma_f32_32x32x16_bf16(afrag[1][tap], xf,
                                                           acc[1][nt], 0, 0, 0);
    }
  }
  {
    us8 one = {};
    if (qh == 0) one[0] = 0x3F80;
    bf16x8 xone = __builtin_bit_cast(bf16x8, one);
#pragma unroll
    for (int nt = 0; nt < 2; ++nt) {
      acc[0][nt] = __builtin_amdgcn_mfma_f32_32x32x16_bf16(afrag[0][9], xone,
                                                           acc[0][nt], 0, 0, 0);
      acc[1][nt] = __builtin_amdgcn_mfma_f32_32x32x16_bf16(afrag[1][9], xone,
                                                           acc[1][nt], 0, 0, 0);
    }
  }
  float vmin[2];
#pragma unroll
  for (int nt = 0; nt < 2; ++nt) {
    float v = acc[0][nt][0];
#pragma unroll
    for (int e = 1; e < 16; ++e) v = fminf(v, acc[0][nt][e]);
#pragma unroll
    for (int e = 0; e < 16; ++e) v = fminf(v, acc[1][nt][e]);
    v = fminf(v, __shfl_xor(v, 32, 64));
    vmin[nt] = fast_tanh(fast_tanh(v));
  }
  float res = (lane < 32) ? vmin[0] : vmin[1];
  int ow = wave * 64 + lane;
  if (ow < OWW) out[((size_t)n * OHH + oh) * OWW + ow] = res;
}

extern "C" void kernel_launch(void* const* d_in, const int* in_sizes, int n_in,
                              void* d_out, int out_size, void* d_ws, size_t ws_size,
                              hipStream_t stream) {
  const float* x = (const float*)d_in[0];
  const float* w = (const float*)d_in[1];
  const float* b = (const float*)d_in[2];
  float* out = (float*)d_out;
  if (ws_size >= WS_NEEDED) {
    unsigned short* wp = (unsigned short*)d_ws;
    prep_w<<<dim3((WP_SHORTS + 255) / 256), dim3(256), 0, stream>>>(w, b, wp);
    conv_fused<<<dim3(N_IMG * NSTRIP), dim3(512), 0, stream>>>(x, wp, out);
  } else {
    conv_min_tanh<<<dim3(N_IMG * OHH), dim3(256), 0, stream>>>(x, w, b, out);
  }
}